// Round 14
// baseline (96.345 us; speedup 1.0000x reference)
//
#include <hip/hip_runtime.h>
#include <hip/hip_bf16.h>

#define M_DIM 2048   // size
#define K_DIM 2048   // prev_size
#define N_DIM 8192   // batch

#define BM 128
#define BN 128
#define BK 64             // i8 bytes per K-tile
#define NT (K_DIM / BK)   // 32 K-tiles

typedef __attribute__((ext_vector_type(4))) int i32x4;

// async global->LDS: each lane contributes 16B; LDS dest is wave-uniform base,
// hardware writes base + lane*16 (linear).
static __device__ __forceinline__ void stage1k(const unsigned char* g, void* l) {
    __builtin_amdgcn_global_load_lds(
        (const __attribute__((address_space(1))) void*)g,
        (__attribute__((address_space(3))) void*)l, 16, 0, 0);
}

// ---- fused preprocessing: transp+quant / row-softmax+quant / table-c -------
// (unchanged from R13 — runs at the ~19 us HBM floor)
__global__ __launch_bounds__(256) void prep_kernel(
    const float* __restrict__ prev, const float* __restrict__ Wa,
    const float* __restrict__ Wb, const float* __restrict__ TW,
    unsigned char* __restrict__ Pa, unsigned char* __restrict__ Pb,
    unsigned char* __restrict__ Pt,
    float* __restrict__ SA, float* __restrict__ SB, float4* __restrict__ C4)
{
    __shared__ unsigned char tile[64][80];
    __shared__ float redm[4], reds[4];
    const int bx = blockIdx.x;
    const int t = threadIdx.x;

    if (bx < 4096) {
        const int n0 = (bx & 127) * 64;
        const int k0 = (bx >> 7) * 64;
        const int kb = (t >> 4) * 4;
        const int nb = (t & 15) * 4;
        unsigned int pk0 = 0, pk1 = 0, pk2 = 0, pk3 = 0;
#pragma unroll
        for (int j = 0; j < 4; ++j) {
            float4 v = *(const float4*)(prev + (size_t)(k0 + kb + j) * N_DIM + n0 + nb);
            pk0 |= (unsigned int)(unsigned char)(int)(127.f * v.x + 0.5f) << (8 * j);
            pk1 |= (unsigned int)(unsigned char)(int)(127.f * v.y + 0.5f) << (8 * j);
            pk2 |= (unsigned int)(unsigned char)(int)(127.f * v.z + 0.5f) << (8 * j);
            pk3 |= (unsigned int)(unsigned char)(int)(127.f * v.w + 0.5f) << (8 * j);
        }
        *(unsigned int*)&tile[nb + 0][kb] = pk0;
        *(unsigned int*)&tile[nb + 1][kb] = pk1;
        *(unsigned int*)&tile[nb + 2][kb] = pk2;
        *(unsigned int*)&tile[nb + 3][kb] = pk3;
        __syncthreads();
        const int n = t >> 2;
        const int k16 = (t & 3) * 16;
        int4 v = *(const int4*)&tile[n][k16];
        *(int4*)(Pt + (size_t)(n0 + n) * K_DIM + k0 + k16) = v;
        return;
    }
    if (bx < 8192) {
        const int r = bx - 4096;
        const int row = r & 2047;
        const int isB = r >> 11;
        const float* W = isB ? Wb : Wa;
        unsigned char* P = isB ? Pb : Pa;
        float* S = isB ? SB : SA;
        const float* w = W + (size_t)row * K_DIM + t * 8;
        float4 v0 = *(const float4*)(w);
        float4 v1 = *(const float4*)(w + 4);
        float x[8] = {v0.x, v0.y, v0.z, v0.w, v1.x, v1.y, v1.z, v1.w};

        float m = x[0];
#pragma unroll
        for (int i = 1; i < 8; ++i) m = fmaxf(m, x[i]);
#pragma unroll
        for (int off = 32; off >= 1; off >>= 1) m = fmaxf(m, __shfl_xor(m, off));
        const int wid = t >> 6;
        if ((t & 63) == 0) redm[wid] = m;
        __syncthreads();
        m = fmaxf(fmaxf(redm[0], redm[1]), fmaxf(redm[2], redm[3]));

        float s = 0.f;
#pragma unroll
        for (int i = 0; i < 8; ++i) { x[i] = __expf(x[i] - m); s += x[i]; }
#pragma unroll
        for (int off = 32; off >= 1; off >>= 1) s += __shfl_xor(s, off);
        if ((t & 63) == 0) reds[wid] = s;
        __syncthreads();
        s = reds[0] + reds[1] + reds[2] + reds[3];

        union { unsigned char u[8]; int2 v; } pk;
#pragma unroll
        for (int i = 0; i < 8; ++i)
            pk.u[i] = (unsigned char)(int)(127.f * x[i] + 0.5f);
        *(int2*)(P + (size_t)row * K_DIM + t * 8) = pk.v;
        if (t == 0) S[row] = 1.f / (16129.f * s);
        return;
    }
    const int s = (bx - 8192) * 256 + t;
    if (s >= M_DIM) return;
    float x[16];
    float m = -1e30f;
#pragma unroll
    for (int tt = 0; tt < 16; ++tt) { x[tt] = TW[tt * M_DIM + s]; m = fmaxf(m, x[tt]); }
    float sum = 0.f;
#pragma unroll
    for (int tt = 0; tt < 16; ++tt) { x[tt] = __expf(x[tt] - m); sum += x[tt]; }
    const float inv = 1.0f / sum;
    const float c0a[16] = {0,0,0,0,0,0,0,0, 1,1,1,1,1,1,1,1};
    const float cAa[16] = {0,0,1,1,0,0,1,1, -1,-1,0,0,-1,-1,0,0};
    const float cBa[16] = {0,0,0,0,1,1,1,1, -1,-1,-1,-1,0,0,0,0};
    const float cXa[16] = {0,1,-1,0,-1,0,-2,-1, 1,2,0,1,0,1,-1,0};
    float c0 = 0.f, cA = 0.f, cB = 0.f, cX = 0.f;
#pragma unroll
    for (int tt = 0; tt < 16; ++tt) {
        const float p = x[tt] * inv;
        c0 += p * c0a[tt]; cA += p * cAa[tt]; cB += p * cBa[tt]; cX += p * cXa[tt];
    }
    C4[s] = make_float4(c0, cA, cB, cX);
}

// ---- dual i8 GEMM, 128x128 tile, tri-buffered, 2 blocks/CU -----------------
// All data-path components verified through R13 (i8 quant, sigma(r)=(r>>1)&3
// swizzle with pre-swizzled source, stage1k, mfma_i32_16x16x64_i8, epilogue;
// 0 bank conflicts). Change vs R13: one 8-wave/128KB-LDS barrier domain ->
// TWO 4-wave/72KB domains per CU. Within a block, reads serialize before the
// MFMA cluster; the SIBLING block's MFMA covers them (m114 inter-block
// overlap). R11's version of this failed due to vmcnt(0) + ~650cyc lead;
// here: tri-buffer, 2-tile stage lead (~4800 cyc >> 900 HBM), counted
// vmcnt(6) in steady state, never 0.
//
// Per kt: STAGE(t+2) -> buf[(t+2)%3] (6 calls, 4KB each, issued FIRST);
// read 12 b128 from buf[t%3]; 32 MFMA; vmcnt(6) (outstanding = stage(t+1) 6
// + stage(t+2) 6 -> drains t+1); barrier (publishes t+1 for next iter).
// Reads of buf[t] licensed: stage(t) drained by guard @ end-(t-1) + barrier.
// WAR: stage(t+2) overwrites buf[(t-1)%3], whose reads executed during kt-1
// (>=1 barrier + ~900cyc stage latency margin; same class as R9/R13).

#define MFMA8(ACC, FA, FP, MI0)                                                \
    _Pragma("unroll") for (int mi = (MI0); mi < (MI0) + 2; ++mi)               \
    _Pragma("unroll") for (int ni = 0; ni < 4; ++ni)                           \
        ACC[mi][ni] = __builtin_amdgcn_mfma_i32_16x16x64_i8(                   \
            FA[mi], FP[ni], ACC[mi][ni], 0, 0, 0);

#define STAGE(T) do { const int b_ = (T) % 3;                                  \
    const size_t o_ = (size_t)(T) * BK;                                        \
    stage1k(gPa + o_,               &sPa[b_][wid * 16][0]);                    \
    stage1k(gPa + o_ + 64 * K_DIM,  &sPa[b_][64 + wid * 16][0]);               \
    stage1k(gPb + o_,               &sPb[b_][wid * 16][0]);                    \
    stage1k(gPb + o_ + 64 * K_DIM,  &sPb[b_][64 + wid * 16][0]);               \
    stage1k(gPt + o_,               &sPt[b_][wid * 16][0]);                    \
    stage1k(gPt + o_ + 64 * K_DIM,  &sPt[b_][64 + wid * 16][0]); } while (0)

__global__ __launch_bounds__(256, 2) void logic_gemm_kernel(
    const unsigned char* __restrict__ Pa,   // [M][K] u8
    const unsigned char* __restrict__ Pb,   // [M][K] u8
    const unsigned char* __restrict__ Pt,   // prevT [N][K] u8
    const float4* __restrict__ C4,          // [M]
    const float* __restrict__ SA,           // [M] dequant scales
    const float* __restrict__ SB,           // [M]
    float* __restrict__ out)                // [M][N]
{
    __shared__ unsigned char sPa[3][128][64];   // 24 KB
    __shared__ unsigned char sPb[3][128][64];   // 24 KB
    __shared__ unsigned char sPt[3][128][64];   // 24 KB

    const int m0 = blockIdx.y * BM;
    const int n0 = blockIdx.x * BN;
    const int t = threadIdx.x;
    const int wid = t >> 6, lane = t & 63;
    const int wr = wid >> 1, wc = wid & 1;   // 2x2 waves, 64x64 out each
    const int lq = lane >> 4, lr = lane & 15;

    // staging: lane -> region row (lane>>2), pre-swizzled source col (bytes)
    const int srow = lane >> 2;                               // 0..15
    const int scol = (((lane & 3) ^ ((lane >> 3) & 3)) << 4); // {0,16,32,48} B
    const unsigned char* gPa = Pa + (size_t)(m0 + wid * 16 + srow) * K_DIM + scol;
    const unsigned char* gPb = Pb + (size_t)(m0 + wid * 16 + srow) * K_DIM + scol;
    const unsigned char* gPt = Pt + (size_t)(n0 + wid * 16 + srow) * K_DIM + scol;

    // ds_read byte offsets (swizzled): row*64 + 16*(lq ^ sigma(row)),
    // sigma(r) = (r>>1)&3 -> conflict-free (verified R4..R13)
    const int cswz = (lq ^ ((lr >> 1) & 3)) << 4;
    const int roA = (wr * 64 + lr) * 64 + cswz;
    const int roP = (wc * 64 + lr) * 64 + cswz;

    i32x4 accA[4][4] = {};
    i32x4 accB[4][4] = {};
    i32x4 fa[4], fb[4], fp[4];

    // prologue: stage tiles 0,1 (12 calls); drain tile 0 (leave tile 1's 6).
    STAGE(0);
    STAGE(1);
    asm volatile("s_waitcnt vmcnt(6)" ::: "memory");
    __builtin_amdgcn_s_barrier();

    for (int kt = 0; kt < NT; ++kt) {
        const int bcur = kt % 3;
        const char* bA = (const char*)&sPa[bcur][0][0];
        const char* bB = (const char*)&sPb[bcur][0][0];
        const char* bP = (const char*)&sPt[bcur][0][0];

        if (kt + 2 < NT) STAGE(kt + 2);      // issue early (T3 recipe)

#pragma unroll
        for (int i = 0; i < 4; ++i) fa[i] = *(const i32x4*)(bA + roA + i * 1024);
#pragma unroll
        for (int i = 0; i < 4; ++i) fp[i] = *(const i32x4*)(bP + roP + i * 1024);
#pragma unroll
        for (int i = 0; i < 4; ++i) fb[i] = *(const i32x4*)(bB + roA + i * 1024);

        __builtin_amdgcn_s_setprio(1);
        MFMA8(accA, fa, fp, 0);
        MFMA8(accA, fa, fp, 2);
        MFMA8(accB, fb, fp, 0);
        MFMA8(accB, fb, fp, 2);
        __builtin_amdgcn_s_setprio(0);

        if (kt < NT - 2) asm volatile("s_waitcnt vmcnt(6)" ::: "memory");
        else             asm volatile("s_waitcnt vmcnt(0)" ::: "memory");
        __builtin_amdgcn_s_barrier();
    }

    // epilogue: dequant + gate polynomial
#pragma unroll
    for (int mi = 0; mi < 4; ++mi) {
#pragma unroll
        for (int i = 0; i < 4; ++i) {
            const int row = m0 + wr * 64 + mi * 16 + lq * 4 + i;
            const float4 c = C4[row];
            const float sa = SA[row];
            const float sb = SB[row];
#pragma unroll
            for (int ni = 0; ni < 4; ++ni) {
                const int col = n0 + wc * 64 + ni * 16 + lr;
                const float Av = (float)accA[mi][ni][i] * sa;
                const float Bv = (float)accB[mi][ni][i] * sb;
                out[(size_t)row * N_DIM + col] = c.x + c.y * Av + c.z * Bv + c.w * Av * Bv;
            }
        }
    }
}

extern "C" void kernel_launch(void* const* d_in, const int* in_sizes, int n_in,
                              void* d_out, int out_size, void* d_ws, size_t ws_size,
                              hipStream_t stream) {
    const float* prev = (const float*)d_in[0];   // [2048][8192]
    const float* Wa   = (const float*)d_in[1];   // [2048][2048]
    const float* Wb   = (const float*)d_in[2];   // [2048][2048]
    const float* TW   = (const float*)d_in[3];   // [16][2048]
    float* out = (float*)d_out;                  // [2048][8192]

    char* ws = (char*)d_ws;
    unsigned char* Pa = (unsigned char*)(ws);                       //  4 MiB
    unsigned char* Pb = (unsigned char*)(ws + (size_t)(4u << 20));  //  4 MiB
    unsigned char* Pt = (unsigned char*)(ws + (size_t)(8u << 20));  // 16 MiB
    float4* C4 = (float4*)(ws + (size_t)(24u << 20));               // 32 KiB
    float*  SA = (float*)(ws + (size_t)(24u << 20) + (32u << 10));  //  8 KiB
    float*  SB = (float*)(ws + (size_t)(24u << 20) + (64u << 10));  //  8 KiB

    prep_kernel<<<dim3(8200), 256, 0, stream>>>(prev, Wa, Wb, TW,
                                                Pa, Pb, Pt, SA, SB, C4);
    logic_gemm_kernel<<<dim3(N_DIM / BN, M_DIM / BM), 256, 0, stream>>>(Pa, Pb, Pt, C4, SA, SB, out);
}

// Round 15
// 95.498 us; speedup vs baseline: 1.0089x; 1.0089x over previous
//
#include <hip/hip_runtime.h>
#include <hip/hip_bf16.h>

#define M_DIM 2048   // size
#define K_DIM 2048   // prev_size
#define N_DIM 8192   // batch

#define BM 128
#define BN 256
#define BK 64             // i8 bytes per K-tile
#define NT (K_DIM / BK)   // 32 K-tiles

typedef __attribute__((ext_vector_type(4))) int i32x4;

// async global->LDS: each lane contributes 16B; LDS dest is wave-uniform base,
// hardware writes base + lane*16 (linear).
static __device__ __forceinline__ void stage1k(const unsigned char* g, void* l) {
    __builtin_amdgcn_global_load_lds(
        (const __attribute__((address_space(1))) void*)g,
        (__attribute__((address_space(3))) void*)l, 16, 0, 0);
}

// ---- fused preprocessing: transp+quant / row-softmax+quant / table-c -------
// (unchanged from R13 — runs at the ~19 us HBM floor)
__global__ __launch_bounds__(256) void prep_kernel(
    const float* __restrict__ prev, const float* __restrict__ Wa,
    const float* __restrict__ Wb, const float* __restrict__ TW,
    unsigned char* __restrict__ Pa, unsigned char* __restrict__ Pb,
    unsigned char* __restrict__ Pt,
    float* __restrict__ SA, float* __restrict__ SB, float4* __restrict__ C4)
{
    __shared__ unsigned char tile[64][80];
    __shared__ float redm[4], reds[4];
    const int bx = blockIdx.x;
    const int t = threadIdx.x;

    if (bx < 4096) {
        const int n0 = (bx & 127) * 64;
        const int k0 = (bx >> 7) * 64;
        const int kb = (t >> 4) * 4;
        const int nb = (t & 15) * 4;
        unsigned int pk0 = 0, pk1 = 0, pk2 = 0, pk3 = 0;
#pragma unroll
        for (int j = 0; j < 4; ++j) {
            float4 v = *(const float4*)(prev + (size_t)(k0 + kb + j) * N_DIM + n0 + nb);
            pk0 |= (unsigned int)(unsigned char)(int)(127.f * v.x + 0.5f) << (8 * j);
            pk1 |= (unsigned int)(unsigned char)(int)(127.f * v.y + 0.5f) << (8 * j);
            pk2 |= (unsigned int)(unsigned char)(int)(127.f * v.z + 0.5f) << (8 * j);
            pk3 |= (unsigned int)(unsigned char)(int)(127.f * v.w + 0.5f) << (8 * j);
        }
        *(unsigned int*)&tile[nb + 0][kb] = pk0;
        *(unsigned int*)&tile[nb + 1][kb] = pk1;
        *(unsigned int*)&tile[nb + 2][kb] = pk2;
        *(unsigned int*)&tile[nb + 3][kb] = pk3;
        __syncthreads();
        const int n = t >> 2;
        const int k16 = (t & 3) * 16;
        int4 v = *(const int4*)&tile[n][k16];
        *(int4*)(Pt + (size_t)(n0 + n) * K_DIM + k0 + k16) = v;
        return;
    }
    if (bx < 8192) {
        const int r = bx - 4096;
        const int row = r & 2047;
        const int isB = r >> 11;
        const float* W = isB ? Wb : Wa;
        unsigned char* P = isB ? Pb : Pa;
        float* S = isB ? SB : SA;
        const float* w = W + (size_t)row * K_DIM + t * 8;
        float4 v0 = *(const float4*)(w);
        float4 v1 = *(const float4*)(w + 4);
        float x[8] = {v0.x, v0.y, v0.z, v0.w, v1.x, v1.y, v1.z, v1.w};

        float m = x[0];
#pragma unroll
        for (int i = 1; i < 8; ++i) m = fmaxf(m, x[i]);
#pragma unroll
        for (int off = 32; off >= 1; off >>= 1) m = fmaxf(m, __shfl_xor(m, off));
        const int wid = t >> 6;
        if ((t & 63) == 0) redm[wid] = m;
        __syncthreads();
        m = fmaxf(fmaxf(redm[0], redm[1]), fmaxf(redm[2], redm[3]));

        float s = 0.f;
#pragma unroll
        for (int i = 0; i < 8; ++i) { x[i] = __expf(x[i] - m); s += x[i]; }
#pragma unroll
        for (int off = 32; off >= 1; off >>= 1) s += __shfl_xor(s, off);
        if ((t & 63) == 0) reds[wid] = s;
        __syncthreads();
        s = reds[0] + reds[1] + reds[2] + reds[3];

        union { unsigned char u[8]; int2 v; } pk;
#pragma unroll
        for (int i = 0; i < 8; ++i)
            pk.u[i] = (unsigned char)(int)(127.f * x[i] + 0.5f);
        *(int2*)(P + (size_t)row * K_DIM + t * 8) = pk.v;
        if (t == 0) S[row] = 1.f / (16129.f * s);
        return;
    }
    const int s = (bx - 8192) * 256 + t;
    if (s >= M_DIM) return;
    float x[16];
    float m = -1e30f;
#pragma unroll
    for (int tt = 0; tt < 16; ++tt) { x[tt] = TW[tt * M_DIM + s]; m = fmaxf(m, x[tt]); }
    float sum = 0.f;
#pragma unroll
    for (int tt = 0; tt < 16; ++tt) { x[tt] = __expf(x[tt] - m); sum += x[tt]; }
    const float inv = 1.0f / sum;
    const float c0a[16] = {0,0,0,0,0,0,0,0, 1,1,1,1,1,1,1,1};
    const float cAa[16] = {0,0,1,1,0,0,1,1, -1,-1,0,0,-1,-1,0,0};
    const float cBa[16] = {0,0,0,0,1,1,1,1, -1,-1,-1,-1,0,0,0,0};
    const float cXa[16] = {0,1,-1,0,-1,0,-2,-1, 1,2,0,1,0,1,-1,0};
    float c0 = 0.f, cA = 0.f, cB = 0.f, cX = 0.f;
#pragma unroll
    for (int tt = 0; tt < 16; ++tt) {
        const float p = x[tt] * inv;
        c0 += p * c0a[tt]; cA += p * cAa[tt]; cB += p * cBa[tt]; cX += p * cXa[tt];
    }
    C4[s] = make_float4(c0, cA, cB, cX);
}

// ---- dual i8 GEMM, fat-wave tile (128st x 128), quad-buffer, 4 waves -------
// Wave tile: 64 A-rows + 64 B-rows x 128 cols -> 16 b128 LDS reads per 64
// MFMA (0.25 reads/MFMA vs R13's 0.375). Per-CU per kt: LDS reads 768 cyc
// << MFMA 1306 cyc -> LDS fits UNDER the MFMA pipe; overlap via intra-wave
// ILP (reads for kt+1 issue behind kt's MFMA cluster), not TLP.
// acc 256 VGPR + 2 frag sets 128 + addr ~40 = ~424 (< 450 no-spill, m08);
// 1 wave/SIMD, 256-thr block, 1 block/CU.
//
// Quad-buffered LDS (4 x 32KB = 128KB), stage lead 3 tiles, guard vmcnt(8)
// (never 0 until tail). Ledger (8 stage calls/kt, FIFO):
//  - guard@kt: after STAGE(kt+3), outstanding = stage(kt+2)+stage(kt+3) = 16
//    -> vmcnt(8) drains stage(kt+2); barrier@kt publishes buf[(kt+2)%4],
//    read during kt+1 (reads are 1 kt ahead). OK.
//  - reads@kt target buf[(kt+1)%4]: stage(kt+1) drained by guard@kt-1,
//    published by barrier@kt-1. OK.
//  - WAR: STAGE(kt+3) overwrites buf[(kt-1)%4], whose frag reads happened
//    during kt-2 and were lgkm-drained before their consuming MFMAs at kt-1,
//    i.e. before barrier@kt-1 < stage issue@kt. OK.
// Tail: kt >= NT-3 -> vmcnt(0). sigma(r)=(r>>1)&3 swizzle verbatim (0
// conflicts, R4..R13); mfma_i32_16x16x64_i8; i8 quant verbatim.

#define MFMA32(ACC, FX, FP)                                                    \
    _Pragma("unroll") for (int mi = 0; mi < 4; ++mi)                           \
    _Pragma("unroll") for (int ni = 0; ni < 8; ++ni)                           \
        ACC[mi][ni] = __builtin_amdgcn_mfma_i32_16x16x64_i8(                   \
            FX[mi], FP[ni], ACC[mi][ni], 0, 0, 0);

#define STAGE(T, B) do { const size_t o_ = (size_t)(T) * BK;                   \
    stage1k(gPa + o_,                &sPa[B][wid * 16][0]);                    \
    stage1k(gPa + o_ + 64 * K_DIM,   &sPa[B][64 + wid * 16][0]);               \
    stage1k(gPb + o_,                &sPb[B][wid * 16][0]);                    \
    stage1k(gPb + o_ + 64 * K_DIM,   &sPb[B][64 + wid * 16][0]);               \
    stage1k(gPt + o_,                &sPt[B][wid * 16][0]);                    \
    stage1k(gPt + o_ + 64 * K_DIM,   &sPt[B][64 + wid * 16][0]);               \
    stage1k(gPt + o_ + 128 * K_DIM,  &sPt[B][128 + wid * 16][0]);              \
    stage1k(gPt + o_ + 192 * K_DIM,  &sPt[B][192 + wid * 16][0]); } while (0)

#define READ_FRAGS(FA, FB, FP, B) do {                                         \
    const char* bA_ = (const char*)&sPa[B][0][0];                              \
    const char* bB_ = (const char*)&sPb[B][0][0];                              \
    const char* bP_ = (const char*)&sPt[B][0][0];                              \
    _Pragma("unroll") for (int i = 0; i < 4; ++i)                              \
        FA[i] = *(const i32x4*)(bA_ + roA + i * 1024);                         \
    _Pragma("unroll") for (int i = 0; i < 4; ++i)                              \
        FB[i] = *(const i32x4*)(bB_ + roA + i * 1024);                         \
    _Pragma("unroll") for (int i = 0; i < 8; ++i)                              \
        FP[i] = *(const i32x4*)(bP_ + roP + i * 1024);                         \
} while (0)

#define KT_STEP(KT, BJ, FA_C, FB_C, FP_C, FA_N, FB_N, FP_N) do {               \
    if ((KT) + 3 < NT) STAGE((KT) + 3, (((BJ) + 3) & 3));                      \
    __builtin_amdgcn_s_setprio(1);                                             \
    MFMA32(accA, FA_C, FP_C);                                                  \
    __builtin_amdgcn_s_setprio(0);                                             \
    if ((KT) + 1 < NT) READ_FRAGS(FA_N, FB_N, FP_N, (((BJ) + 1) & 3));         \
    __builtin_amdgcn_s_setprio(1);                                             \
    MFMA32(accB, FB_C, FP_C);                                                  \
    __builtin_amdgcn_s_setprio(0);                                             \
    if ((KT) < NT - 3) asm volatile("s_waitcnt vmcnt(8)" ::: "memory");        \
    else               asm volatile("s_waitcnt vmcnt(0)" ::: "memory");        \
    __builtin_amdgcn_s_barrier();                                              \
} while (0)

__global__ __launch_bounds__(256, 1) void logic_gemm_kernel(
    const unsigned char* __restrict__ Pa,   // [M][K] u8
    const unsigned char* __restrict__ Pb,   // [M][K] u8
    const unsigned char* __restrict__ Pt,   // prevT [N][K] u8
    const float4* __restrict__ C4,          // [M]
    const float* __restrict__ SA,           // [M] dequant scales
    const float* __restrict__ SB,           // [M]
    float* __restrict__ out)                // [M][N]
{
    __shared__ unsigned char sPa[4][128][64];   // 32 KB
    __shared__ unsigned char sPb[4][128][64];   // 32 KB
    __shared__ unsigned char sPt[4][256][64];   // 64 KB

    const int m0 = blockIdx.y * BM;
    const int n0 = blockIdx.x * BN;
    const int t = threadIdx.x;
    const int wid = t >> 6, lane = t & 63;
    const int wr = wid >> 1, wc = wid & 1;   // 2M x 2N waves; 64x128 out x2
    const int lq = lane >> 4, lr = lane & 15;

    // staging: lane -> region row (lane>>2), pre-swizzled source col (bytes)
    const int srow = lane >> 2;                               // 0..15
    const int scol = (((lane & 3) ^ ((lane >> 3) & 3)) << 4); // {0,16,32,48} B
    const unsigned char* gPa = Pa + (size_t)(m0 + wid * 16 + srow) * K_DIM + scol;
    const unsigned char* gPb = Pb + (size_t)(m0 + wid * 16 + srow) * K_DIM + scol;
    const unsigned char* gPt = Pt + (size_t)(n0 + wid * 16 + srow) * K_DIM + scol;

    // ds_read byte offsets (swizzled): row*64 + 16*(lq ^ sigma(row)),
    // sigma(r) = (r>>1)&3 -> conflict-free (verified R4..R13)
    const int cswz = (lq ^ ((lr >> 1) & 3)) << 4;
    const int roA = (wr * 64 + lr) * 64 + cswz;    // within [128][64B]
    const int roP = (wc * 128 + lr) * 64 + cswz;   // within [256][64B]

    i32x4 accA[4][8] = {};
    i32x4 accB[4][8] = {};
    i32x4 faE[4], fbE[4], fpE[8], faO[4], fbO[4], fpO[8];

    // prologue: stage tiles 0,1,2 (24 loads); drain 0,1 (leave tile 2's 8);
    // barrier publishes buf0,buf1; pre-read even set <- buf0 (kt=0).
    STAGE(0, 0); STAGE(1, 1); STAGE(2, 2);
    asm volatile("s_waitcnt vmcnt(8)" ::: "memory");
    __builtin_amdgcn_s_barrier();
    READ_FRAGS(faE, fbE, fpE, 0);

    for (int it = 0; it < NT / 4; ++it) {
        const int kt = it * 4;
        KT_STEP(kt + 0, 0, faE, fbE, fpE, faO, fbO, fpO);
        KT_STEP(kt + 1, 1, faO, fbO, fpO, faE, fbE, fpE);
        KT_STEP(kt + 2, 2, faE, fbE, fpE, faO, fbO, fpO);
        KT_STEP(kt + 3, 3, faO, fbO, fpO, faE, fbE, fpE);
    }

    // epilogue: dequant + gate polynomial
#pragma unroll
    for (int mi = 0; mi < 4; ++mi) {
#pragma unroll
        for (int i = 0; i < 4; ++i) {
            const int row = m0 + wr * 64 + mi * 16 + lq * 4 + i;
            const float4 c = C4[row];
            const float sa = SA[row];
            const float sb = SB[row];
#pragma unroll
            for (int ni = 0; ni < 8; ++ni) {
                const int col = n0 + wc * 128 + ni * 16 + lr;
                const float Av = (float)accA[mi][ni][i] * sa;
                const float Bv = (float)accB[mi][ni][i] * sb;
                out[(size_t)row * N_DIM + col] = c.x + c.y * Av + c.z * Bv + c.w * Av * Bv;
            }
        }
    }
}

extern "C" void kernel_launch(void* const* d_in, const int* in_sizes, int n_in,
                              void* d_out, int out_size, void* d_ws, size_t ws_size,
                              hipStream_t stream) {
    const float* prev = (const float*)d_in[0];   // [2048][8192]
    const float* Wa   = (const float*)d_in[1];   // [2048][2048]
    const float* Wb   = (const float*)d_in[2];   // [2048][2048]
    const float* TW   = (const float*)d_in[3];   // [16][2048]
    float* out = (float*)d_out;                  // [2048][8192]

    char* ws = (char*)d_ws;
    unsigned char* Pa = (unsigned char*)(ws);                       //  4 MiB
    unsigned char* Pb = (unsigned char*)(ws + (size_t)(4u << 20));  //  4 MiB
    unsigned char* Pt = (unsigned char*)(ws + (size_t)(8u << 20));  // 16 MiB
    float4* C4 = (float4*)(ws + (size_t)(24u << 20));               // 32 KiB
    float*  SA = (float*)(ws + (size_t)(24u << 20) + (32u << 10));  //  8 KiB
    float*  SB = (float*)(ws + (size_t)(24u << 20) + (64u << 10));  //  8 KiB

    prep_kernel<<<dim3(8200), 256, 0, stream>>>(prev, Wa, Wb, TW,
                                                Pa, Pb, Pt, SA, SB, C4);
    logic_gemm_kernel<<<dim3(N_DIM / BN, M_DIM / BM), 256, 0, stream>>>(Pa, Pb, Pt, C4, SA, SB, out);
}

// Round 16
// 82.907 us; speedup vs baseline: 1.1621x; 1.1519x over previous
//
#include <hip/hip_runtime.h>
#include <hip/hip_bf16.h>

#define M_DIM 2048   // size
#define K_DIM 2048   // prev_size
#define N_DIM 8192   // batch

#define BM 128
#define BN 256
#define BK 128            // i8 elements per K-tile (two kh halves of 64)
#define NT (K_DIM / BK)   // 16 K-tiles

typedef __attribute__((ext_vector_type(4))) int i32x4;

// async global->LDS: each lane contributes 16B; LDS dest is wave-uniform base,
// hardware writes base + lane*16 (linear).
static __device__ __forceinline__ void stage1k(const unsigned char* g, void* l) {
    __builtin_amdgcn_global_load_lds(
        (const __attribute__((address_space(1))) void*)g,
        (__attribute__((address_space(3))) void*)l, 16, 0, 0);
}

// ---- fused preprocessing: transp+quant / row-softmax+quant / table-c -------
// blocks [0,4096): prev [K][N] f32 -> prevT [N][K] u8 (x127, transposed)
// blocks [4096,8192): softmax rows of Wa/Wb -> u8 probs + per-row scale
// blocks [8192,8200): table softmax -> C4 gate coefficients
__global__ __launch_bounds__(256) void prep_kernel(
    const float* __restrict__ prev, const float* __restrict__ Wa,
    const float* __restrict__ Wb, const float* __restrict__ TW,
    unsigned char* __restrict__ Pa, unsigned char* __restrict__ Pb,
    unsigned char* __restrict__ Pt,
    float* __restrict__ SA, float* __restrict__ SB, float4* __restrict__ C4)
{
    __shared__ unsigned char tile[64][80];
    __shared__ float redm[4], reds[4];
    const int bx = blockIdx.x;
    const int t = threadIdx.x;

    if (bx < 4096) {
        // ---- transpose + quantize (4x4 micro-block per thread) ----
        const int n0 = (bx & 127) * 64;
        const int k0 = (bx >> 7) * 64;
        const int kb = (t >> 4) * 4;
        const int nb = (t & 15) * 4;
        unsigned int pk0 = 0, pk1 = 0, pk2 = 0, pk3 = 0;
#pragma unroll
        for (int j = 0; j < 4; ++j) {
            float4 v = *(const float4*)(prev + (size_t)(k0 + kb + j) * N_DIM + n0 + nb);
            pk0 |= (unsigned int)(unsigned char)(int)(127.f * v.x + 0.5f) << (8 * j);
            pk1 |= (unsigned int)(unsigned char)(int)(127.f * v.y + 0.5f) << (8 * j);
            pk2 |= (unsigned int)(unsigned char)(int)(127.f * v.z + 0.5f) << (8 * j);
            pk3 |= (unsigned int)(unsigned char)(int)(127.f * v.w + 0.5f) << (8 * j);
        }
        *(unsigned int*)&tile[nb + 0][kb] = pk0;
        *(unsigned int*)&tile[nb + 1][kb] = pk1;
        *(unsigned int*)&tile[nb + 2][kb] = pk2;
        *(unsigned int*)&tile[nb + 3][kb] = pk3;
        __syncthreads();
        const int n = t >> 2;
        const int k16 = (t & 3) * 16;
        int4 v = *(const int4*)&tile[n][k16];
        *(int4*)(Pt + (size_t)(n0 + n) * K_DIM + k0 + k16) = v;
        return;
    }
    if (bx < 8192) {
        // ---- row softmax + u8 quant: a_k = round(127*exp(x-m)) ----
        const int r = bx - 4096;             // 0..4095
        const int row = r & 2047;
        const int isB = r >> 11;
        const float* W = isB ? Wb : Wa;
        unsigned char* P = isB ? Pb : Pa;
        float* S = isB ? SB : SA;
        const float* w = W + (size_t)row * K_DIM + t * 8;
        float4 v0 = *(const float4*)(w);
        float4 v1 = *(const float4*)(w + 4);
        float x[8] = {v0.x, v0.y, v0.z, v0.w, v1.x, v1.y, v1.z, v1.w};

        float m = x[0];
#pragma unroll
        for (int i = 1; i < 8; ++i) m = fmaxf(m, x[i]);
#pragma unroll
        for (int off = 32; off >= 1; off >>= 1) m = fmaxf(m, __shfl_xor(m, off));
        const int wid = t >> 6;
        if ((t & 63) == 0) redm[wid] = m;
        __syncthreads();
        m = fmaxf(fmaxf(redm[0], redm[1]), fmaxf(redm[2], redm[3]));

        float s = 0.f;
#pragma unroll
        for (int i = 0; i < 8; ++i) { x[i] = __expf(x[i] - m); s += x[i]; }
#pragma unroll
        for (int off = 32; off >= 1; off >>= 1) s += __shfl_xor(s, off);
        if ((t & 63) == 0) reds[wid] = s;
        __syncthreads();
        s = reds[0] + reds[1] + reds[2] + reds[3];

        union { unsigned char u[8]; int2 v; } pk;
#pragma unroll
        for (int i = 0; i < 8; ++i)
            pk.u[i] = (unsigned char)(int)(127.f * x[i] + 0.5f);
        *(int2*)(P + (size_t)row * K_DIM + t * 8) = pk.v;
        if (t == 0) S[row] = 1.f / (16129.f * s);
        return;
    }
    // ---- table softmax -> gate coefficients ----
    const int s = (bx - 8192) * 256 + t;
    if (s >= M_DIM) return;
    float x[16];
    float m = -1e30f;
#pragma unroll
    for (int tt = 0; tt < 16; ++tt) { x[tt] = TW[tt * M_DIM + s]; m = fmaxf(m, x[tt]); }
    float sum = 0.f;
#pragma unroll
    for (int tt = 0; tt < 16; ++tt) { x[tt] = __expf(x[tt] - m); sum += x[tt]; }
    const float inv = 1.0f / sum;
    const float c0a[16] = {0,0,0,0,0,0,0,0, 1,1,1,1,1,1,1,1};
    const float cAa[16] = {0,0,1,1,0,0,1,1, -1,-1,0,0,-1,-1,0,0};
    const float cBa[16] = {0,0,0,0,1,1,1,1, -1,-1,-1,-1,0,0,0,0};
    const float cXa[16] = {0,1,-1,0,-1,0,-2,-1, 1,2,0,1,0,1,-1,0};
    float c0 = 0.f, cA = 0.f, cB = 0.f, cX = 0.f;
#pragma unroll
    for (int tt = 0; tt < 16; ++tt) {
        const float p = x[tt] * inv;
        c0 += p * c0a[tt]; cA += p * cAa[tt]; cB += p * cBa[tt]; cX += p * cXa[tt];
    }
    C4[s] = make_float4(c0, cA, cB, cX);
}

// ------------- dual i8 GEMM, merged 2-phase schedule + gate epilogue --------
// Champion configuration (R13: GEMM 64.5 us, MfmaUtil 43.5%, 0 conflicts).
// LDS regions [128/256 rows][64 B], sigma(r)=(r>>1)&3 16B-slot swizzle
// (write: pre-swizzled global col; read: same XOR). Tile covers K=128 i8.
// Frag sets double-buffered, STATIC names (rule #20).
//
// Phase I(kt):  16 MFMA (set0) | reads set1 <- [buf][1] | stage C,D(kt+1)
//               (-> [buf^1][1]) | vmcnt(4) | 16 MFMA (set0) | barrier
// Phase II(kt): 16 MFMA (set1) | reads set0 <- [buf^1][0] | stage A,B(kt+2)
//               (-> [buf][0]) | vmcnt(4) | 16 MFMA (set1) | barrier
//
// WAR: C,D(kt+1) target last consumed start-II(kt-1); A,B(kt+2) target last
// consumed start-I(kt) - both >= 1 barrier before stage issue. Publishes
// (FIFO, 8 stage calls/kt): guard@I drains A,B(kt+1) for mid-II reads;
// guard@II drains C,D(kt+1) for mid-I(kt+1) reads. Tails: vmcnt(0).

#define MFMA8(ACC, FA, FP, MI0)                                                \
    _Pragma("unroll") for (int mi = (MI0); mi < (MI0) + 2; ++mi)               \
    _Pragma("unroll") for (int ni = 0; ni < 4; ++ni)                           \
        ACC[mi][ni] = __builtin_amdgcn_mfma_i32_16x16x64_i8(                   \
            FA[mi], FP[ni], ACC[mi][ni], 0, 0, 0);

#define STAGE_A(T) do { const int b_ = (T) & 1; const size_t o_ = (size_t)(T) * BK; \
    stage1k(gPa + o_,  &sPa[b_][0][wid * 16][0]);                              \
    stage1k(gPt0 + o_, &sPt[b_][0][wid * 16][0]); } while (0)
#define STAGE_B(T) do { const int b_ = (T) & 1; const size_t o_ = (size_t)(T) * BK; \
    stage1k(gPt1 + o_, &sPt[b_][0][128 + wid * 16][0]);                        \
    stage1k(gPb + o_,  &sPb[b_][0][wid * 16][0]); } while (0)
#define STAGE_C(T) do { const int b_ = (T) & 1; const size_t o_ = (size_t)(T) * BK + 64; \
    stage1k(gPa + o_,  &sPa[b_][1][wid * 16][0]);                              \
    stage1k(gPt0 + o_, &sPt[b_][1][wid * 16][0]); } while (0)
#define STAGE_D(T) do { const int b_ = (T) & 1; const size_t o_ = (size_t)(T) * BK + 64; \
    stage1k(gPt1 + o_, &sPt[b_][1][128 + wid * 16][0]);                        \
    stage1k(gPb + o_,  &sPb[b_][1][wid * 16][0]); } while (0)

#define RD_SET(FA, FB, FP, BA, BB, BP)                                         \
    _Pragma("unroll") for (int i = 0; i < 4; ++i)                              \
        FA[i] = *(const i32x4*)((BA) + roA + i * 1024);                        \
    _Pragma("unroll") for (int i = 0; i < 4; ++i)                              \
        FP[i] = *(const i32x4*)((BP) + roP + i * 1024);                        \
    _Pragma("unroll") for (int i = 0; i < 4; ++i)                              \
        FB[i] = *(const i32x4*)((BB) + roA + i * 1024);

__global__ __launch_bounds__(512, 2) void logic_gemm_kernel(
    const unsigned char* __restrict__ Pa,   // [M][K] u8
    const unsigned char* __restrict__ Pb,   // [M][K] u8
    const unsigned char* __restrict__ Pt,   // prevT [N][K] u8
    const float4* __restrict__ C4,          // [M]
    const float* __restrict__ SA,           // [M] dequant scales
    const float* __restrict__ SB,           // [M]
    float* __restrict__ out)                // [M][N]
{
    __shared__ unsigned char sPa[2][2][128][64];   // 32 KB
    __shared__ unsigned char sPb[2][2][128][64];   // 32 KB
    __shared__ unsigned char sPt[2][2][256][64];   // 64 KB

    const int m0 = blockIdx.y * BM;
    const int n0 = blockIdx.x * BN;
    const int t = threadIdx.x;
    const int wid = t >> 6, lane = t & 63;
    const int wr = wid >> 2, wc = wid & 3;   // 2M x 4N waves, 64x64 out each
    const int lq = lane >> 4, lr = lane & 15;

    // staging: lane -> region row (lane>>2), pre-swizzled source col (bytes)
    const int srow = lane >> 2;                               // 0..15
    const int scol = (((lane & 3) ^ ((lane >> 3) & 3)) << 4); // {0,16,32,48} B
    const unsigned char* gPa  = Pa + (size_t)(m0 + wid * 16 + srow) * K_DIM + scol;
    const unsigned char* gPb  = Pb + (size_t)(m0 + wid * 16 + srow) * K_DIM + scol;
    const unsigned char* gPt0 = Pt + (size_t)(n0 + wid * 16 + srow) * K_DIM + scol;
    const unsigned char* gPt1 = gPt0 + (size_t)128 * K_DIM;

    // ds_read byte offsets (swizzled): row*64 + 16*(lq ^ sigma(row)),
    // sigma(r) = (r>>1)&3 -> conflict-free (verified R4..R13)
    const int cswz = (lq ^ ((lr >> 1) & 3)) << 4;
    const int roA = (wr * 64 + lr) * 64 + cswz;   // within [128][64B] region
    const int roP = (wc * 64 + lr) * 64 + cswz;   // within [256][64B] region

    i32x4 accA[4][4] = {};
    i32x4 accB[4][4] = {};
    i32x4 fa0[4], fb0[4], fp0[4], fa1[4], fb1[4], fp1[4];

    // prologue: A,B(0), C,D(0), A,B(1) = 12 calls; drain tile 0 (8 calls),
    // leave A,B(1) in flight; barrier; read set0 <- tile0 kh0.
    STAGE_A(0); STAGE_B(0); STAGE_C(0); STAGE_D(0);
    STAGE_A(1); STAGE_B(1);
    asm volatile("s_waitcnt vmcnt(4)" ::: "memory");
    __builtin_amdgcn_s_barrier();
    RD_SET(fa0, fb0, fp0,
           (const char*)&sPa[0][0][0][0],
           (const char*)&sPb[0][0][0][0],
           (const char*)&sPt[0][0][0][0]);

    for (int kt = 0; kt < NT; ++kt) {
        const int buf = kt & 1;
        const char* bA1 = (const char*)&sPa[buf][1][0][0];
        const char* bB1 = (const char*)&sPb[buf][1][0][0];
        const char* bP1 = (const char*)&sPt[buf][1][0][0];
        const char* nA0 = (const char*)&sPa[buf ^ 1][0][0][0];
        const char* nB0 = (const char*)&sPb[buf ^ 1][0][0][0];
        const char* nP0 = (const char*)&sPt[buf ^ 1][0][0][0];

        // ---------------- phase I: kh0 (set0) ----------------
        __builtin_amdgcn_s_setprio(1);
        MFMA8(accA, fa0, fp0, 0);
        MFMA8(accA, fa0, fp0, 2);
        __builtin_amdgcn_s_setprio(0);
        RD_SET(fa1, fb1, fp1, bA1, bB1, bP1);          // tile kt kh1
        if (kt + 1 < NT) { STAGE_C(kt + 1); STAGE_D(kt + 1); }
        if (kt < NT - 1) asm volatile("s_waitcnt vmcnt(4)" ::: "memory");
        else             asm volatile("s_waitcnt vmcnt(0)" ::: "memory");
        __builtin_amdgcn_s_setprio(1);
        MFMA8(accB, fb0, fp0, 0);
        MFMA8(accB, fb0, fp0, 2);
        __builtin_amdgcn_s_setprio(0);
        __builtin_amdgcn_s_barrier();

        // ---------------- phase II: kh1 (set1) ----------------
        __builtin_amdgcn_s_setprio(1);
        MFMA8(accA, fa1, fp1, 0);
        MFMA8(accA, fa1, fp1, 2);
        __builtin_amdgcn_s_setprio(0);
        if (kt + 1 < NT) RD_SET(fa0, fb0, fp0, nA0, nB0, nP0);   // tile kt+1 kh0
        if (kt + 2 < NT) { STAGE_A(kt + 2); STAGE_B(kt + 2); }
        if (kt < NT - 2) asm volatile("s_waitcnt vmcnt(4)" ::: "memory");
        else             asm volatile("s_waitcnt vmcnt(0)" ::: "memory");
        __builtin_amdgcn_s_setprio(1);
        MFMA8(accB, fb1, fp1, 0);
        MFMA8(accB, fb1, fp1, 2);
        __builtin_amdgcn_s_setprio(0);
        __builtin_amdgcn_s_barrier();
    }

    // epilogue: dequant + gate polynomial
#pragma unroll
    for (int mi = 0; mi < 4; ++mi) {
#pragma unroll
        for (int i = 0; i < 4; ++i) {
            const int row = m0 + wr * 64 + mi * 16 + lq * 4 + i;
            const float4 c = C4[row];
            const float sa = SA[row];
            const float sb = SB[row];
#pragma unroll
            for (int ni = 0; ni < 4; ++ni) {
                const int col = n0 + wc * 64 + ni * 16 + lr;
                const float Av = (float)accA[mi][ni][i] * sa;
                const float Bv = (float)accB[mi][ni][i] * sb;
                out[(size_t)row * N_DIM + col] = c.x + c.y * Av + c.z * Bv + c.w * Av * Bv;
            }
        }
    }
}

extern "C" void kernel_launch(void* const* d_in, const int* in_sizes, int n_in,
                              void* d_out, int out_size, void* d_ws, size_t ws_size,
                              hipStream_t stream) {
    const float* prev = (const float*)d_in[0];   // [2048][8192]
    const float* Wa   = (const float*)d_in[1];   // [2048][2048]
    const float* Wb   = (const float*)d_in[2];   // [2048][2048]
    const float* TW   = (const float*)d_in[3];   // [16][2048]
    float* out = (float*)d_out;                  // [2048][8192]

    char* ws = (char*)d_ws;
    unsigned char* Pa = (unsigned char*)(ws);                       //  4 MiB
    unsigned char* Pb = (unsigned char*)(ws + (size_t)(4u << 20));  //  4 MiB
    unsigned char* Pt = (unsigned char*)(ws + (size_t)(8u << 20));  // 16 MiB
    float4* C4 = (float4*)(ws + (size_t)(24u << 20));               // 32 KiB
    float*  SA = (float*)(ws + (size_t)(24u << 20) + (32u << 10));  //  8 KiB
    float*  SB = (float*)(ws + (size_t)(24u << 20) + (64u << 10));  //  8 KiB

    prep_kernel<<<dim3(8200), 256, 0, stream>>>(prev, Wa, Wb, TW,
                                                Pa, Pb, Pt, SA, SB, C4);
    logic_gemm_kernel<<<dim3(N_DIM / BN, M_DIM / BM), 512, 0, stream>>>(Pa, Pb, Pt, C4, SA, SB, out);
}